// Round 14
// baseline (388.952 us; speedup 1.0000x reference)
//
#include <hip/hip_runtime.h>
#include <hip/hip_fp16.h>

#define D 128
#define CAP 64
#define NBKT 512
#define CHUNK 4096
#define BKTCAP 5120

typedef _Float16 f16x8 __attribute__((ext_vector_type(8)));
typedef float f32x4 __attribute__((ext_vector_type(4)));

// ---- phase A: bin edges into 512 dst-buckets; extra blocks pack W1/W2 ----
__global__ __launch_bounds__(256) void k_bin(const int* __restrict__ ei,
        const float* __restrict__ ew, int* __restrict__ gcur,
        int2* __restrict__ gbkt, int e, int nbin,
        const float* __restrict__ W1, const float* __restrict__ W2,
        __half* __restrict__ Wpk1, __half* __restrict__ Wpk2) {
    if (blockIdx.x >= nbin) {
        int gidx = (blockIdx.x - nbin) * 256 + threadIdx.x;
        if (gidx >= 4096) return;
        const float* W = (gidx < 2048) ? W1 : W2;
        __half* P = (gidx < 2048) ? Wpk1 : Wpk2;
        int idx = gidx & 2047;
        int lane = idx & 63, nt = (idx >> 6) & 7, ks = idx >> 9;
        int col = nt * 16 + (lane & 15);
        int kb = ks * 32 + (lane >> 4) * 8;
        #pragma unroll
        for (int j = 0; j < 8; ++j)
            P[idx * 8 + j] = __float2half(W[(kb + j) * D + col]);
        return;
    }
    __shared__ int hist[NBKT];
    __shared__ int base[NBKT];
    int t = threadIdx.x;
    int b0 = blockIdx.x * CHUNK;
    int cnt = min(CHUNK, e - b0);
    for (int i = t; i < NBKT; i += 256) hist[i] = 0;
    __syncthreads();
    int meta[16]; float w[16]; int pos[16]; int bkt[16];
    #pragma unroll
    for (int j = 0; j < 16; ++j) {
        int li = t + j * 256;
        bkt[j] = -1;
        if (li < cnt) {
            int i = b0 + li;
            int d = ei[e + i];
            int s = ei[i];
            bkt[j] = d >> 8;
            meta[j] = s | ((d & 255) << 24);
            w[j] = ew[i];
            pos[j] = atomicAdd(&hist[bkt[j]], 1);
        }
    }
    __syncthreads();
    for (int i = t; i < NBKT; i += 256)
        if (hist[i] > 0) base[i] = atomicAdd(&gcur[i], hist[i]);
    __syncthreads();
    #pragma unroll
    for (int j = 0; j < 16; ++j) {
        if (bkt[j] >= 0) {
            int idx = base[bkt[j]] + pos[j];
            if (idx < BKTCAP)
                gbkt[(size_t)bkt[j] * BKTCAP + idx] =
                    make_int2(meta[j], __float_as_int(w[j]));
        }
    }
}

// ---- phase B: bucket records -> packed 4B meta rows; dis; slice-major xh ----
// meta word: src[16:0] | fp16bits(w)[14:0] << 17   (w >= 0, sign bit 0)
__global__ __launch_bounds__(1024) void k_scat2(const int2* __restrict__ gbkt,
        const int* __restrict__ gcur, const float2* __restrict__ X,
        int* __restrict__ mslot, int* __restrict__ rsc, float* __restrict__ dis,
        __half* __restrict__ xh, int n) {
    __shared__ int cur[256];
    __shared__ float wsum[256];
    __shared__ float disv[256];
    int bkt = blockIdx.x;
    int nodebase = bkt << 8;
    int t = threadIdx.x;
    int cnt = min(gcur[bkt], BKTCAP);
    if (t < 256) { cur[t] = 0; wsum[t] = 0.f; }
    __syncthreads();
    for (int i = t; i < cnt; i += 1024) {
        int2 r = gbkt[(size_t)bkt * BKTCAP + i];
        int dl = (unsigned)r.x >> 24;
        int pos = atomicAdd(&cur[dl], 1);
        float w = __int_as_float(r.y);
        atomicAdd(&wsum[dl], w);
        if (pos < CAP) {
            unsigned hb = (unsigned)__half_as_ushort(__float2half(w));
            mslot[(((size_t)(nodebase + dl)) << 6) + pos] =
                (r.x & 0x1FFFF) | (int)(hb << 17);
        }
    }
    __syncthreads();
    if (t < 256) {
        int v = nodebase + t;
        float dv = 1.f;
        if (v < n) {
            dv = rsqrtf(1.0f + wsum[t]);
            dis[v] = dv;
            rsc[v] = cur[t];
        }
        disv[t] = dv;
    }
    __syncthreads();
    size_t n32 = (size_t)n * 32;
    int nrow = min(256, n - nodebase);
    for (int idx = t; idx < nrow * 64; idx += 1024) {
        int r = idx >> 6, dp = idx & 63;       // dp = pair of dims (2*dp, 2*dp+1)
        int grow = nodebase + r;
        float dv2 = disv[r];
        float2 f = X[((size_t)grow << 6) + dp];
        __half2 h = __floats2half2_rn(dv2 * f.x, dv2 * f.y);
        *(__half2*)(xh + (size_t)(dp >> 4) * n32 + (size_t)grow * 32 + ((dp & 15) << 1)) = h;
    }
}

// ---- D-sliced agg: slice s of out[v] = dv*( Hs_s[v] + sum w_e*Hs_s[src] ) ----
// Hs slice-major [4][n][32] fp16 (64B rows). Wave: 1 node-slice; 16 edges/gather.
__global__ __launch_bounds__(256) void k_agg(const __half* __restrict__ Hs,
        const int* __restrict__ mslot, const int* __restrict__ rsc,
        const float* __restrict__ dis, __half* __restrict__ outp, int n) {
    int sub = blockIdx.x & 7;
    int slice = sub >> 1;                      // XCD pair {2s,2s+1} per slice
    int nodeblock = (blockIdx.x >> 3) * 2 + (sub & 1);
    int wid = threadIdx.x >> 6, lane = threadIdx.x & 63;
    int v = nodeblock * 4 + wid;
    if (v >= n) return;
    int eg = lane >> 2;                        // edge within group of 16
    int quad = lane & 3;                       // 16B sub-block of the 64B row
    int c = min(rsc[v], 62);
    int c1 = c + 1;                            // + virtual self edge (j=0)
    const int* mrow = mslot + ((size_t)v << 6);

    int mm;                                    // lane j holds logical edge j
    if (lane == 0) mm = v | (int)(0x3C00u << 17);   // self, w=1.0
    else if (lane < c1) mm = mrow[lane - 1];
    else mm = v;                               // padding: w=0, own (hot) row

    size_t n32 = (size_t)n * 32;
    const char* Hb = (const char*)(Hs + (size_t)slice * n32);

    float acc[8];
    #pragma unroll
    for (int d = 0; d < 8; ++d) acc[d] = 0.f;

    for (int j0 = 0; j0 < c1; j0 += 16) {
        int mv = __shfl(mm, j0 + eg);          // <= 63 always
        int src = mv & 0x1FFFF;
        float w = __half2float(__ushort_as_half((unsigned short)((unsigned)mv >> 17)));
        f16x8 g = *(const f16x8*)(Hb + ((size_t)src << 6) + (quad << 4));
        #pragma unroll
        for (int d = 0; d < 8; ++d) acc[d] = fmaf(w, (float)g[d], acc[d]);
    }
    #pragma unroll
    for (int off = 4; off <= 32; off <<= 1) {
        #pragma unroll
        for (int d = 0; d < 8; ++d) acc[d] += __shfl_xor(acc[d], off);
    }
    if (eg == 0) {
        float dv = dis[v];
        union { f16x8 v8; __half2 h[4]; } o;
        #pragma unroll
        for (int d = 0; d < 4; ++d)
            o.h[d] = __floats2half2_rn(dv * acc[2 * d], dv * acc[2 * d + 1]);
        *(f16x8*)((char*)(outp + (size_t)slice * n32) + ((size_t)v << 6) + (quad << 4)) = o.v8;
    }
}

// ---- MFMA GEMM: C = prelu(A @ W + b); A slice-major [4][n][32] fp16 ----
// HALF_OUT: write slice-major fp16 pre-scaled by dis; else row-major f32.
template <bool HALF_OUT>
__global__ __launch_bounds__(256) void k_gemm(const __half* __restrict__ A,
        const __half* __restrict__ Wpk, const float* __restrict__ b,
        const float* __restrict__ ap, const float* __restrict__ dis,
        void* __restrict__ Cv, int n) {
    int t = threadIdx.x;
    int wv = t >> 6, lane = t & 63;
    int base = blockIdx.x * 64 + wv * 16;
    int row = base + (lane & 15);
    int rowc = min(row, n - 1);
    int kg = lane >> 4;
    size_t n32 = (size_t)n * 32;

    f16x8 afr[4];                              // K-step ks == slice ks
    #pragma unroll
    for (int ks = 0; ks < 4; ++ks)
        afr[ks] = *(const f16x8*)(A + (size_t)ks * n32 + (size_t)rowc * 32 + kg * 8);

    const f16x8* Wp = (const f16x8*)Wpk;
    f32x4 acc[8];
    #pragma unroll
    for (int nt = 0; nt < 8; ++nt) acc[nt] = (f32x4){0.f, 0.f, 0.f, 0.f};

    #pragma unroll
    for (int ks = 0; ks < 4; ++ks) {
        #pragma unroll
        for (int nt = 0; nt < 8; ++nt) {
            f16x8 bfr = Wp[(ks * 8 + nt) * 64 + lane];
            acc[nt] = __builtin_amdgcn_mfma_f32_16x16x32_f16(afr[ks], bfr, acc[nt], 0, 0, 0);
        }
    }

    int c0 = lane & 15;
    int r0 = base + (lane >> 4) * 4;
    float dv[4];
    #pragma unroll
    for (int q = 0; q < 4; ++q)
        dv[q] = HALF_OUT ? dis[min(r0 + q, n - 1)] : 1.0f;
    #pragma unroll
    for (int nt = 0; nt < 8; ++nt) {
        int col = nt * 16 + c0;
        float bb = b[col], aa = ap[col];
        #pragma unroll
        for (int q = 0; q < 4; ++q) {
            int r = r0 + q;
            if (r < n) {
                float z = acc[nt][q] + bb;
                z = (z >= 0.f) ? z : aa * z;
                if (HALF_OUT) {
                    // slice-major: slice = col>>5, offset = col&31
                    ((__half*)Cv)[(size_t)(nt >> 1) * n32 + (size_t)r * 32 +
                                  ((nt & 1) * 16 + c0)] = __float2half(dv[q] * z);
                } else {
                    ((float*)Cv)[(size_t)r * D + col] = z;
                }
            }
        }
    }
}

// ---------------- launch ----------------

extern "C" void kernel_launch(void* const* d_in, const int* in_sizes, int n_in,
                              void* d_out, int out_size, void* d_ws, size_t ws_size,
                              hipStream_t stream) {
    const float* x  = (const float*)d_in[0];
    const int*   ei = (const int*)d_in[1];
    const float* ew = (const float*)d_in[2];
    const float* W1 = (const float*)d_in[3];
    const float* b1 = (const float*)d_in[4];
    const float* W2 = (const float*)d_in[5];
    const float* b2 = (const float*)d_in[6];
    const float* ap = (const float*)d_in[7];

    int n = in_sizes[0] / D;
    int e = in_sizes[2];

    int*     gcur  = (int*)d_ws;                              // NBKT
    float*   dis   = (float*)(gcur + NBKT);                   // n
    int*     rsc   = (int*)(dis + n);                         // n
    int2*    gbkt  = (int2*)(rsc + n);                        // NBKT*BKTCAP (21 MB)
    int*     mslot = (int*)(gbkt + (size_t)NBKT * BKTCAP);    // n*64 int (25.6 MB)
    __half*  xh    = (__half*)(mslot + (size_t)n * 64);       // [4][n][32] (25.6 MB)
    __half*  z1h   = xh + (size_t)n * 128;                    // [4][n][32] (25.6 MB)
    __half*  ah    = z1h + (size_t)n * 128;                   // [4][n][32] (25.6 MB)
    __half*  Wpk1  = ah + (size_t)n * 128;                    // 32 KB
    __half*  Wpk2  = Wpk1 + 16384;                            // 32 KB
    float*   out   = (float*)d_out;

    int nbin = (e + CHUNK - 1) / CHUNK;
    int nbb  = (n + 255) / 256;
    int NB   = (n + 3) / 4;                   // node-blocks (4 nodes each)
    int nba  = ((NB + 1) / 2) * 8;            // agg grid: x4 slices, x2 halves
    int nbg  = (n + 63) / 64;

    hipMemsetAsync(gcur, 0, NBKT * sizeof(int), stream);
    k_bin<<<nbin + 16, 256, 0, stream>>>(ei, ew, gcur, gbkt, e, nbin, W1, W2, Wpk1, Wpk2);
    k_scat2<<<nbb, 1024, 0, stream>>>(gbkt, gcur, (const float2*)x, mslot, rsc, dis, xh, n);

    // layer 1: ah = agg(xh) ; z1h = dis * prelu(ah @ W1 + b1)  (fp16, slice-major)
    k_agg<<<nba, 256, 0, stream>>>(xh, mslot, rsc, dis, ah, n);
    k_gemm<true><<<nbg, 256, 0, stream>>>(ah, Wpk1, b1, ap, dis, (void*)z1h, n);
    // layer 2: ah = agg(z1h) ; out = prelu(ah @ W2 + b2)       (f32 row-major)
    k_agg<<<nba, 256, 0, stream>>>(z1h, mslot, rsc, dis, ah, n);
    k_gemm<false><<<nbg, 256, 0, stream>>>(ah, Wpk2, b2, ap, dis, (void*)out, n);
}

// Round 15
// 216.961 us; speedup vs baseline: 1.7927x; 1.7927x over previous
//
#include <hip/hip_runtime.h>
#include <hip/hip_fp16.h>

#define D 128
#define CAP 64
#define NBKT 512
#define CHUNK 4096
#define BKTCAP 5120

typedef _Float16 f16x8 __attribute__((ext_vector_type(8)));
typedef float f32x4 __attribute__((ext_vector_type(4)));

// ---- phase A: bin edges into 512 dst-buckets; extra blocks pack W1/W2 ----
__global__ __launch_bounds__(256) void k_bin(const int* __restrict__ ei,
        const float* __restrict__ ew, int* __restrict__ gcur,
        int2* __restrict__ gbkt, int e, int nbin,
        const float* __restrict__ W1, const float* __restrict__ W2,
        __half* __restrict__ Wpk1, __half* __restrict__ Wpk2) {
    if (blockIdx.x >= nbin) {
        int gidx = (blockIdx.x - nbin) * 256 + threadIdx.x;
        if (gidx >= 4096) return;
        const float* W = (gidx < 2048) ? W1 : W2;
        __half* P = (gidx < 2048) ? Wpk1 : Wpk2;
        int idx = gidx & 2047;
        int lane = idx & 63, nt = (idx >> 6) & 7, ks = idx >> 9;
        int col = nt * 16 + (lane & 15);
        int kb = ks * 32 + (lane >> 4) * 8;
        #pragma unroll
        for (int j = 0; j < 8; ++j)
            P[idx * 8 + j] = __float2half(W[(kb + j) * D + col]);
        return;
    }
    __shared__ int hist[NBKT];
    __shared__ int base[NBKT];
    int t = threadIdx.x;
    int b0 = blockIdx.x * CHUNK;
    int cnt = min(CHUNK, e - b0);
    for (int i = t; i < NBKT; i += 256) hist[i] = 0;
    __syncthreads();
    int meta[16]; float w[16]; int pos[16]; int bkt[16];
    #pragma unroll
    for (int j = 0; j < 16; ++j) {
        int li = t + j * 256;
        bkt[j] = -1;
        if (li < cnt) {
            int i = b0 + li;
            int d = ei[e + i];
            int s = ei[i];
            bkt[j] = d >> 8;
            meta[j] = s | ((d & 255) << 24);
            w[j] = ew[i];
            pos[j] = atomicAdd(&hist[bkt[j]], 1);
        }
    }
    __syncthreads();
    for (int i = t; i < NBKT; i += 256)
        if (hist[i] > 0) base[i] = atomicAdd(&gcur[i], hist[i]);
    __syncthreads();
    #pragma unroll
    for (int j = 0; j < 16; ++j) {
        if (bkt[j] >= 0) {
            int idx = base[bkt[j]] + pos[j];
            if (idx < BKTCAP)
                gbkt[(size_t)bkt[j] * BKTCAP + idx] =
                    make_int2(meta[j], __float_as_int(w[j]));
        }
    }
}

// ---- phase B: bucket records -> packed 4B meta rows (padded, 64/node) ----
// meta word: src[16:0] | fp16bits(w)[14:0] << 17  (w >= 0 so sign bit 0)
// Fused: weighted degree -> dis, count -> rsc, x -> pre-scaled fp16.
__global__ __launch_bounds__(1024) void k_scat2(const int2* __restrict__ gbkt,
        const int* __restrict__ gcur, const float2* __restrict__ X,
        int* __restrict__ mslot, int* __restrict__ rsc, float* __restrict__ dis,
        __half2* __restrict__ xh, int n) {
    __shared__ int cur[256];
    __shared__ float wsum[256];
    __shared__ float disv[256];
    int bkt = blockIdx.x;
    int nodebase = bkt << 8;
    int t = threadIdx.x;
    int cnt = min(gcur[bkt], BKTCAP);
    if (t < 256) { cur[t] = 0; wsum[t] = 0.f; }
    __syncthreads();
    for (int i = t; i < cnt; i += 1024) {
        int2 r = gbkt[(size_t)bkt * BKTCAP + i];
        int dl = (unsigned)r.x >> 24;
        int pos = atomicAdd(&cur[dl], 1);
        float w = __int_as_float(r.y);
        atomicAdd(&wsum[dl], w);
        if (pos < CAP) {
            unsigned hb = (unsigned)__half_as_ushort(__float2half(w));
            mslot[(((size_t)(nodebase + dl)) << 6) + pos] =
                (r.x & 0x1FFFF) | (int)(hb << 17);
        }
    }
    __syncthreads();
    if (t < 256) {
        int v = nodebase + t;
        float dv = 1.f;
        if (v < n) {
            dv = rsqrtf(1.0f + wsum[t]);
            dis[v] = dv;
            rsc[v] = cur[t];
        }
        disv[t] = dv;
    }
    __syncthreads();
    int nrow = min(256, n - nodebase);
    size_t rowbase = (size_t)nodebase << 6;
    for (int idx = t; idx < nrow * 64; idx += 1024) {
        float dv2 = disv[idx >> 6];
        float2 f = X[rowbase + idx];
        xh[rowbase + idx] = __floats2half2_rn(dv2 * f.x, dv2 * f.y);
    }
}

// ---- agg batch: NU row-gather instructions in flight (4 edges each) ----
template <int NU>
__device__ __forceinline__ void aggbatch(int j0, int eslot, int dg, int voff,
        float wf, const char* __restrict__ Hc, float (&acc)[8]) {
    int vo[NU]; float w[NU];
    #pragma unroll
    for (int u = 0; u < NU; ++u) {
        int sl = j0 + 4 * u + eslot;     // <= 63 by construction
        vo[u] = __shfl(voff, sl);
        w[u] = __shfl(wf, sl);
    }
    f16x8 g[NU];
    #pragma unroll
    for (int u = 0; u < NU; ++u)
        g[u] = *(const f16x8*)(Hc + vo[u] + (dg << 4));
    #pragma unroll
    for (int u = 0; u < NU; ++u) {
        #pragma unroll
        for (int d = 0; d < 8; ++d)
            acc[d] = fmaf(w[u], (float)g[u][d], acc[d]);
    }
}

// ---- agg: out[v] = dv*( Hs[v] + sum_e w_e*Hs[src] ) ----
// 4 edges per gather instr (16 lanes x 16B), reg-resident 4B meta, 4-deep MLP.
__global__ __launch_bounds__(256) void k_agg(const __half2* __restrict__ Hs,
        const int* __restrict__ mslot, const int* __restrict__ rsc,
        const float* __restrict__ dis, __half2* __restrict__ out, int n) {
    int wid = threadIdx.x >> 6, lane = threadIdx.x & 63;
    int v = blockIdx.x * 4 + wid;
    if (v >= n) return;
    int eslot = lane >> 4;           // 0..3: edge within group of 4
    int dg = lane & 15;              // dim group: dims [8*dg, 8*dg+8)
    int c = min(rsc[v], 62);
    int c1 = c + 1;                  // + virtual self edge (j=0)
    const int* mrow = mslot + ((size_t)v << 6);
    const char* Hc = (const char*)Hs;

    // lane-parallel meta preload: lane j holds logical edge j; w=0 padding
    int mm;
    if (lane == 0) mm = v | (int)(0x3C00u << 17);   // self, w=1.0
    else if (lane < c1) mm = mrow[lane - 1];
    else mm = v;                                     // padding: w=0, own row
    int voff = (mm & 0x1FFFF) << 8;  // byte offset of 256B row
    float wf = (lane != 0 && lane >= c1) ? 0.f
             : __half2float(__ushort_as_half((unsigned short)((unsigned)mm >> 17)));

    float acc[8];
    #pragma unroll
    for (int d = 0; d < 8; ++d) acc[d] = 0.f;

    int j0 = 0;
    for (; j0 + 16 <= c1; j0 += 16) aggbatch<4>(j0, eslot, dg, voff, wf, Hc, acc);
    for (; j0 < c1; j0 += 8)        aggbatch<2>(j0, eslot, dg, voff, wf, Hc, acc);

    #pragma unroll
    for (int d = 0; d < 8; ++d) {
        acc[d] += __shfl_xor(acc[d], 16);
        acc[d] += __shfl_xor(acc[d], 32);
    }
    if (eslot == 0) {
        float dv = dis[v];
        union { f16x8 v8; __half2 h[4]; } o;
        #pragma unroll
        for (int d = 0; d < 4; ++d)
            o.h[d] = __floats2half2_rn(dv * acc[2 * d], dv * acc[2 * d + 1]);
        *(f16x8*)((char*)out + ((size_t)v << 8) + (dg << 4)) = o.v8;
    }
}

// ---- MFMA GEMM: C = prelu(A @ W + b); optional fp16 out pre-scaled by dis ----
template <bool HALF_OUT>
__global__ __launch_bounds__(256) void k_gemm(const __half* __restrict__ A,
        const __half* __restrict__ Wpk, const float* __restrict__ b,
        const float* __restrict__ ap, const float* __restrict__ dis,
        void* __restrict__ Cv, int n) {
    int t = threadIdx.x;
    int wv = t >> 6, lane = t & 63;
    int base = blockIdx.x * 64 + wv * 16;
    int row = base + (lane & 15);
    int rowc = min(row, n - 1);
    int kg = lane >> 4;

    const f16x8* Arow = (const f16x8*)(A + (size_t)rowc * D);
    f16x8 afr[4];
    #pragma unroll
    for (int ks = 0; ks < 4; ++ks) afr[ks] = Arow[ks * 4 + kg];

    const f16x8* Wp = (const f16x8*)Wpk;
    f32x4 acc[8];
    #pragma unroll
    for (int nt = 0; nt < 8; ++nt) acc[nt] = (f32x4){0.f, 0.f, 0.f, 0.f};

    #pragma unroll
    for (int ks = 0; ks < 4; ++ks) {
        #pragma unroll
        for (int nt = 0; nt < 8; ++nt) {
            f16x8 bfr = Wp[(ks * 8 + nt) * 64 + lane];
            acc[nt] = __builtin_amdgcn_mfma_f32_16x16x32_f16(afr[ks], bfr, acc[nt], 0, 0, 0);
        }
    }

    int c0 = lane & 15;
    int r0 = base + (lane >> 4) * 4;
    float dv[4];
    #pragma unroll
    for (int q = 0; q < 4; ++q)
        dv[q] = HALF_OUT ? dis[min(r0 + q, n - 1)] : 1.0f;
    #pragma unroll
    for (int nt = 0; nt < 8; ++nt) {
        int col = nt * 16 + c0;
        float bb = b[col], aa = ap[col];
        #pragma unroll
        for (int q = 0; q < 4; ++q) {
            int r = r0 + q;
            if (r < n) {
                float z = acc[nt][q] + bb;
                z = (z >= 0.f) ? z : aa * z;
                if (HALF_OUT) ((__half*)Cv)[(size_t)r * D + col] = __float2half(dv[q] * z);
                else          ((float*)Cv)[(size_t)r * D + col] = z;
            }
        }
    }
}

// ---------------- launch ----------------

extern "C" void kernel_launch(void* const* d_in, const int* in_sizes, int n_in,
                              void* d_out, int out_size, void* d_ws, size_t ws_size,
                              hipStream_t stream) {
    const float* x  = (const float*)d_in[0];
    const int*   ei = (const int*)d_in[1];
    const float* ew = (const float*)d_in[2];
    const float* W1 = (const float*)d_in[3];
    const float* b1 = (const float*)d_in[4];
    const float* W2 = (const float*)d_in[5];
    const float* b2 = (const float*)d_in[6];
    const float* ap = (const float*)d_in[7];

    int n = in_sizes[0] / D;
    int e = in_sizes[2];

    int*     gcur  = (int*)d_ws;                              // NBKT
    float*   dis   = (float*)(gcur + NBKT);                   // n
    int*     rsc   = (int*)(dis + n);                         // n
    int2*    gbkt  = (int2*)(rsc + n);                        // NBKT*BKTCAP (21 MB)
    int*     mslot = (int*)(gbkt + (size_t)NBKT * BKTCAP);    // n*64 int (25.6 MB)
    __half2* xh    = (__half2*)(mslot + (size_t)n * 64);      // n*64 (25.6 MB)
    __half2* z1h   = xh + (size_t)n * 64;                     // n*64 (25.6 MB)
    __half2* ah    = z1h + (size_t)n * 64;                    // n*64 (25.6 MB)
    __half*  Wpk1  = (__half*)(ah + (size_t)n * 64);          // 32 KB
    __half*  Wpk2  = Wpk1 + 16384;                            // 32 KB
    float*   out   = (float*)d_out;

    int nbin = (e + CHUNK - 1) / CHUNK;
    int nbb  = (n + 255) / 256;
    int nbw  = (n + 3) / 4;
    int nbg  = (n + 63) / 64;

    hipMemsetAsync(gcur, 0, NBKT * sizeof(int), stream);
    k_bin<<<nbin + 16, 256, 0, stream>>>(ei, ew, gcur, gbkt, e, nbin, W1, W2, Wpk1, Wpk2);
    k_scat2<<<nbb, 1024, 0, stream>>>(gbkt, gcur, (const float2*)x, mslot, rsc, dis, xh, n);

    // layer 1: ah = agg(xh) ; z1h = dis * prelu(ah @ W1 + b1)  (fp16, pre-scaled)
    k_agg<<<nbw, 256, 0, stream>>>(xh, mslot, rsc, dis, ah, n);
    k_gemm<true><<<nbg, 256, 0, stream>>>((const __half*)ah, Wpk1, b1, ap, dis, (void*)z1h, n);
    // layer 2: ah = agg(z1h) ; out = prelu(ah @ W2 + b2)       (fp32)
    k_agg<<<nbw, 256, 0, stream>>>(z1h, mslot, rsc, dis, ah, n);
    k_gemm<false><<<nbg, 256, 0, stream>>>((const __half*)ah, Wpk2, b2, ap, dis, (void*)out, n);
}